// Round 7
// baseline (633.488 us; speedup 1.0000x reference)
//
#include <hip/hip_runtime.h>

#define B_ 16
#define N_ 8192
#define D_ 512
#define M_ 1024
#define BT 64
#define SCALE 0.04419417382415922f  // 1/sqrt(512)

typedef __attribute__((ext_vector_type(8))) short short8;
typedef __attribute__((ext_vector_type(4))) short short4v;
typedef __attribute__((ext_vector_type(4))) float f32x4;
typedef __attribute__((ext_vector_type(16))) float f32x16;

__device__ __forceinline__ unsigned short f2bf(float f) {
  unsigned int u = __float_as_uint(f);
  u += 0x7FFFu + ((u >> 16) & 1u);  // RNE
  return (unsigned short)(u >> 16);
}
__device__ __forceinline__ float bf2f(unsigned short h) {
  return __uint_as_float(((unsigned int)h) << 16);
}

// Workgroup barrier that drains ONLY LDS ops (lgkmcnt); leaves global loads
// in flight across the barrier (T4: never vmcnt(0) in the main loop).
// Single asm block = one compiler ordering point ("memory" clobber).
#define LBAR() asm volatile("s_waitcnt lgkmcnt(0)\n\ts_barrier" ::: "memory")

#define MFMA32(a, b, c) __builtin_amdgcn_mfma_f32_32x32x16_bf16((a), (b), (c), 0, 0, 0)

// Fragment-block layouts (1KB contiguous per (tile,kstep), 64 lanes x 16B):
// memTbF: GEMM1 A (scaled mem, rows=m): block (MT 0..31, kk 0..31):
//   elem[l][j] = SCALE*mem[ (kk*16 + (l>>5)*8 + j) ][ MT*32 + (l&31) ]
// memDF:  GEMM2 B (mem, cols=d): block (DT 0..15, kg 0..63):
//   elem[l][j] = mem[ DT*32 + (l&31) ][ kg*16 + (l>>5)*8 + j ]
__global__ void prep_mem_kernel(const float* __restrict__ mem,
                                unsigned short* __restrict__ memTbF,
                                unsigned short* __restrict__ memDF) {
  int t = blockIdx.x * 256 + threadIdx.x;  // 0 .. D*M-1
  int j = t & 7, l = (t >> 3) & 63, blk = t >> 9;
  {
    int kk = blk & 31, MT = blk >> 5;
    int m = MT * 32 + (l & 31);
    int d = kk * 16 + ((l >> 5) << 3) + j;
    memTbF[t] = f2bf(mem[d * M_ + m] * SCALE);
  }
  {
    int kg = blk & 63, DT = blk >> 6;
    int d = DT * 32 + (l & 31);
    int m = kg * 16 + ((l >> 5) << 3) + j;
    memDF[t] = f2bf(mem[d * M_ + m]);
  }
}

__global__ __launch_bounds__(256, 2) void fused_kernel(
    const float* __restrict__ x, const unsigned short* __restrict__ memTbF,
    const unsigned short* __restrict__ memDF, float* __restrict__ out) {
  __shared__ unsigned short sX[32768];  // 64 KB: X bf16, 64 rows x 1024B, XOR-swizzled
  __shared__ unsigned short sPa[8192];  // 16 KB: P bf16, 64 rows x 256B, XOR-swizzled
  float* psums = (float*)sX;            // [4][64], alias (sX dead by then)
  float* sInv = ((float*)sX) + 256;     // [64]

  const int tid = threadIdx.x;
  const int w = tid >> 6;     // wave 0..3
  const int lane = tid & 63;
  const int c31 = lane & 31;
  const int l5 = lane >> 5;
  const int e7 = lane & 7;
  const int t15 = c31 & 15;
  const long t0 = (long)blockIdx.x * BT;

  // ---- Stage X -> bf16 -> swizzled sX (slot' = slot ^ (row&7), 16B slots) ----
  {
    const int row = tid >> 2, cg = tid & 3;
    const int r7 = row & 7;
    const float* xp = x + (t0 + row) * (long)D_ + cg * 128;
    char* sxb = (char*)sX + (row << 10);
#pragma unroll
    for (int j = 0; j < 16; j++) {
      f32x4 v0 = *(const f32x4*)(xp + j * 8);
      f32x4 v1 = *(const f32x4*)(xp + j * 8 + 4);
      short8 o;
      o[0] = (short)f2bf(v0[0]);
      o[1] = (short)f2bf(v0[1]);
      o[2] = (short)f2bf(v0[2]);
      o[3] = (short)f2bf(v0[3]);
      o[4] = (short)f2bf(v1[0]);
      o[5] = (short)f2bf(v1[1]);
      o[6] = (short)f2bf(v1[2]);
      o[7] = (short)f2bf(v1[3]);
      int s = (cg << 4) + j;  // 16B-slot within the 1024B row
      *(short8*)(sxb + ((s ^ r7) << 4)) = o;
    }
  }
  LBAR();

  f32x16 oacc[2][4];  // [tok-tile][d-tile]; C: col d=w*128+d0*32+(l&31), row tok
#pragma unroll
  for (int tt = 0; tt < 2; tt++)
#pragma unroll
    for (int d0 = 0; d0 < 4; d0++) oacc[tt][d0] = (f32x16)0.0f;
  f32x16 sacc[2];     // S chunk: col tok = tt*32+(l&31), row m_local of wave's 32-m slice
  float fsum[2] = {0.f, 0.f};
  short4v po[2][4];   // staged P bf16 packs, written to sPa after barB

  char* const bx0 = (char*)sX + (c31 << 10);
  char* const bx1 = (char*)sX + ((32 + c31) << 10);
  char* const bp0 = (char*)sPa + (c31 << 8);
  char* const bp1 = (char*)sPa + ((32 + c31) << 8);

  // GEMM1 for chunk ch (m-tile MT = ch*4+w): S = memTbF_tile * X
  auto gemm1 = [&](int ch) {
    sacc[0] = (f32x16)0.0f;
    sacc[1] = (f32x16)0.0f;
    const short8* ga = (const short8*)memTbF + (size_t)((ch * 4 + w) * 32) * 64 + lane;
#pragma unroll
    for (int kk = 0; kk < 32; kk++) {
      short8 a = ga[kk * 64];
      int sw = (((kk << 1) | l5) ^ e7) << 4;
      short8 x0 = *(const short8*)(bx0 + sw);
      short8 x1 = *(const short8*)(bx1 + sw);
      sacc[0] = MFMA32(a, x0, sacc[0]);
      sacc[1] = MFMA32(a, x1, sacc[1]);
    }
  };

  // P = exp(S) -> bf16 packs in registers + running fsum (no LDS access)
  auto pgen_compute = [&]() {
#pragma unroll
    for (int tt = 0; tt < 2; tt++) {
      float s = 0.f;
#pragma unroll
      for (int q = 0; q < 16; q++) {
        float p = __expf(sacc[tt][q]);
        unsigned short b = f2bf(p);
        po[tt][q >> 2][q & 3] = (short)b;
        s += bf2f(b);  // sum the rounded values GEMM2 will use
      }
      fsum[tt] += s;
    }
  };
  // Write staged packs to swizzled sPa (rows=tok, 256B; slot' = slot ^ (tok&15))
  auto pgen_write = [&]() {
#pragma unroll
    for (int tt = 0; tt < 2; tt++) {
      int tok = tt * 32 + c31;
      char* base = (char*)sPa + (tok << 8);
#pragma unroll
      for (int q = 0; q < 4; q++) {
        int sl = ((w << 2) | q) ^ t15;
        *(short4v*)(base + (sl << 4) + (l5 << 3)) = po[tt][q];
      }
    }
  };

  gemm1(0);
  pgen_compute();
  pgen_write();

#pragma unroll 1
  for (int c = 0; c < 8; c++) {
    LBAR();  // bar A: sPa(c) ready (LDS-only drain; globals stay in flight)
    if (c == 7 && tid < BT) {
      float s = psums[tid] + psums[64 + tid] + psums[128 + tid] + psums[192 + tid];
      sInv[tid] = 1.0f / s;
    }
    // ---- region: GEMM2(c) interleaved with GEMM1(c+1), prio-boosted ----
    {
      const short8* gb = (const short8*)memDF + ((size_t)(w * 4) * 64 + c * 8) * 64 + lane;
      const bool doG1 = (c < 7);
      const short8* ga = (const short8*)memTbF +
                         (size_t)((((c + 1) & 7) * 4 + w) * 32) * 64 + lane;
      if (doG1) {
        sacc[0] = (f32x16)0.0f;
        sacc[1] = (f32x16)0.0f;
      }
      __builtin_amdgcn_s_setprio(1);
#pragma unroll
      for (int k0 = 0; k0 < 8; k0++) {
        int sp = ((((k0 << 1) | l5) ^ t15) << 4);
        short8 p0 = *(const short8*)(bp0 + sp);
        short8 p1 = *(const short8*)(bp1 + sp);
        short8 b0 = gb[(0 * 64 + k0) * 64];
        short8 b1 = gb[(1 * 64 + k0) * 64];
        short8 b2 = gb[(2 * 64 + k0) * 64];
        short8 b3 = gb[(3 * 64 + k0) * 64];
        oacc[0][0] = MFMA32(p0, b0, oacc[0][0]);
        oacc[1][0] = MFMA32(p1, b0, oacc[1][0]);
        oacc[0][1] = MFMA32(p0, b1, oacc[0][1]);
        oacc[1][1] = MFMA32(p1, b1, oacc[1][1]);
        oacc[0][2] = MFMA32(p0, b2, oacc[0][2]);
        oacc[1][2] = MFMA32(p1, b2, oacc[1][2]);
        oacc[0][3] = MFMA32(p0, b3, oacc[0][3]);
        oacc[1][3] = MFMA32(p1, b3, oacc[1][3]);
        if (doG1) {
#pragma unroll
          for (int kq = 0; kq < 4; kq++) {
            int kk = k0 * 4 + kq;
            short8 a = ga[kk * 64];
            int sw = (((kk << 1) | l5) ^ e7) << 4;
            short8 x0 = *(const short8*)(bx0 + sw);
            short8 x1 = *(const short8*)(bx1 + sw);
            sacc[0] = MFMA32(a, x0, sacc[0]);
            sacc[1] = MFMA32(a, x1, sacc[1]);
          }
        }
      }
      __builtin_amdgcn_s_setprio(0);
    }
    // ---- exp/fsum for chunk c+1 BEFORE barB (overlaps other WG's region) ----
    if (c < 7) pgen_compute();
    LBAR();  // bar B: sPa(c) consumed by all waves
    if (c < 7) {
      pgen_write();
      if (c == 6) {  // fsum now complete; publish per-wave partials (into dead sX)
        float s0 = fsum[0] + __shfl_xor(fsum[0], 32);
        float s1 = fsum[1] + __shfl_xor(fsum[1], 32);
        if (lane < 32) {
          psums[w * 64 + lane] = s0;
          psums[w * 64 + 32 + lane] = s1;
        }
      }
    }
  }

  // ---- Epilogue: O * (1/sum) ----
#pragma unroll
  for (int tt = 0; tt < 2; tt++) {
#pragma unroll
    for (int q = 0; q < 16; q++) {
      int tok = tt * 32 + (q & 3) + ((q >> 2) << 3) + (l5 << 2);
      float inv = sInv[tok];
      float* op = out + (t0 + tok) * (long)D_ + w * 128 + c31;
#pragma unroll
      for (int d0 = 0; d0 < 4; d0++) op[d0 * 32] = oacc[tt][d0][q] * inv;
    }
  }
}

extern "C" void kernel_launch(void* const* d_in, const int* in_sizes, int n_in,
                              void* d_out, int out_size, void* d_ws, size_t ws_size,
                              hipStream_t stream) {
  const float* x = (const float*)d_in[0];
  const float* mem = (const float*)d_in[1];
  float* out = (float*)d_out;
  unsigned short* memTbF = (unsigned short*)d_ws;          // 1 MB frag-layout (scaled)
  unsigned short* memDF = memTbF + (size_t)D_ * M_;        // 1 MB frag-layout

  hipLaunchKernelGGL(prep_mem_kernel, dim3((D_ * M_) / 256), dim3(256), 0, stream,
                     mem, memTbF, memDF);
  hipLaunchKernelGGL(fused_kernel, dim3((B_ * N_) / BT), dim3(256), 0, stream,
                     x, memTbF, memDF, out);
}

// Round 8
// 539.599 us; speedup vs baseline: 1.1740x; 1.1740x over previous
//
#include <hip/hip_runtime.h>

#define B_ 16
#define N_ 8192
#define D_ 512
#define M_ 1024
#define BT 64
#define SCALE 0.04419417382415922f  // 1/sqrt(512)

typedef __attribute__((ext_vector_type(8))) short short8;
typedef __attribute__((ext_vector_type(4))) short short4v;
typedef __attribute__((ext_vector_type(4))) float f32x4;
typedef __attribute__((ext_vector_type(16))) float f32x16;

__device__ __forceinline__ unsigned short f2bf(float f) {
  unsigned int u = __float_as_uint(f);
  u += 0x7FFFu + ((u >> 16) & 1u);  // RNE
  return (unsigned short)(u >> 16);
}
__device__ __forceinline__ float bf2f(unsigned short h) {
  return __uint_as_float(((unsigned int)h) << 16);
}

#define MFMA32(a, b, c) __builtin_amdgcn_mfma_f32_32x32x16_bf16((a), (b), (c), 0, 0, 0)

// Fragment-block layouts (1KB contiguous per (tile,kstep), 64 lanes x 16B):
// memTbF: GEMM1 A (scaled mem, rows=m): block (MT 0..31, kk 0..31):
//   elem[l][j] = SCALE*mem[ (kk*16 + (l>>5)*8 + j) ][ MT*32 + (l&31) ]
// memDF:  GEMM2 B (mem, cols=d): block (DT 0..15, kg 0..63):
//   elem[l][j] = mem[ DT*32 + (l&31) ][ kg*16 + (l>>5)*8 + j ]
__global__ void prep_mem_kernel(const float* __restrict__ mem,
                                unsigned short* __restrict__ memTbF,
                                unsigned short* __restrict__ memDF) {
  int t = blockIdx.x * 256 + threadIdx.x;  // 0 .. D*M-1
  int j = t & 7, l = (t >> 3) & 63, blk = t >> 9;
  {
    int kk = blk & 31, MT = blk >> 5;
    int m = MT * 32 + (l & 31);
    int d = kk * 16 + ((l >> 5) << 3) + j;
    memTbF[t] = f2bf(mem[d * M_ + m] * SCALE);
  }
  {
    int kg = blk & 63, DT = blk >> 6;
    int d = DT * 32 + (l & 31);
    int m = kg * 16 + ((l >> 5) << 3) + j;
    memDF[t] = f2bf(mem[d * M_ + m]);
  }
}

__global__ __launch_bounds__(512, 4) void fused_kernel(
    const float* __restrict__ x, const unsigned short* __restrict__ memTbF,
    const unsigned short* __restrict__ memDF, float* __restrict__ out) {
  __shared__ unsigned short sX[32768];  // 64 KB: X bf16, 64 rows x 1024B, XOR-swizzled
  __shared__ unsigned short sPa[8192];  // 16 KB: P bf16, 64 rows x 256B, XOR-swizzled

  const int tid = threadIdx.x;
  const int w = tid >> 6;      // wave 0..7
  const int lane = tid & 63;
  const int c31 = lane & 31;
  const int l5 = lane >> 5;
  const int e7 = lane & 7;
  const int t15 = lane & 15;
  const int mslot = w & 3;     // GEMM1 m-tile within the 128-m chunk
  const int tslot = w >> 2;    // GEMM1 token-half
  const long t0 = (long)blockIdx.x * BT;

  // ---- Stage X -> bf16 -> swizzled sX (slot' = slot ^ (row&7), 16B slots) ----
  {
    const int row = tid >> 3;       // 0..63
    const int cslot = tid & 7;
    const int r7 = row & 7;
    const float* xp = x + (t0 + row) * (long)D_;
    char* sxb = (char*)sX + (row << 10);
#pragma unroll
    for (int j = 0; j < 8; j++) {
      const int s = cslot + 8 * j;  // 16B-slot 0..63 within the row
      f32x4 v0 = *(const f32x4*)(xp + s * 8);
      f32x4 v1 = *(const f32x4*)(xp + s * 8 + 4);
      short8 o;
      o[0] = (short)f2bf(v0[0]);
      o[1] = (short)f2bf(v0[1]);
      o[2] = (short)f2bf(v0[2]);
      o[3] = (short)f2bf(v0[3]);
      o[4] = (short)f2bf(v1[0]);
      o[5] = (short)f2bf(v1[1]);
      o[6] = (short)f2bf(v1[2]);
      o[7] = (short)f2bf(v1[3]);
      *(short8*)(sxb + ((s ^ r7) << 4)) = o;
    }
  }
  __syncthreads();

  f32x16 oacc[2][2];  // [tt][d0]; C: col d = w*64 + d0*32 + c31, row tok(tt,q,l5)
#pragma unroll
  for (int tt = 0; tt < 2; tt++)
#pragma unroll
    for (int d0 = 0; d0 < 2; d0++) oacc[tt][d0] = (f32x16)0.0f;
  f32x16 sacc;        // S: col tok = tslot*32+c31, row m-local of (chunk, mslot)
  float dsum = 0.f;   // wave 0: sum P rows tt0; wave 1: tt1 (others unused)

  char* const bx = (char*)sX + ((tslot * 32 + c31) << 10);   // GEMM1 X reads
  char* const bp0 = (char*)sPa + (c31 << 8);                 // GEMM2 P, tt0
  char* const bp1 = (char*)sPa + ((32 + c31) << 8);          // GEMM2 P, tt1
  char* const bpw = (char*)sPa + ((tslot * 32 + c31) << 8);  // pgen write base

  // GEMM1 for chunk ch: S(m-tile mslot, token-half tslot) = memTbF_tile * X
  auto gemm1 = [&](int ch) {
    sacc = (f32x16)0.0f;
    const short8* ga =
        (const short8*)memTbF + (size_t)((ch * 4 + mslot) * 32) * 64 + lane;
#pragma unroll
    for (int kk = 0; kk < 32; kk++) {
      short8 a = ga[kk * 64];
      int sw = (((kk << 1) | l5) ^ e7) << 4;
      short8 xv = *(const short8*)(bx + sw);
      sacc = MFMA32(a, xv, sacc);
    }
  };

  // P = exp(S) -> bf16 -> swizzled sPa (no max-sub: gaussian logits, fp32-safe)
  auto pgen = [&]() {
#pragma unroll
    for (int h = 0; h < 4; h++) {
      short4v o;
#pragma unroll
      for (int i = 0; i < 4; i++) o[i] = (short)f2bf(__expf(sacc[h * 4 + i]));
      int sl = ((mslot << 2) | h) ^ t15;
      *(short4v*)(bpw + (sl << 4) + (l5 << 3)) = o;
    }
  };

  gemm1(0);
  pgen();

#pragma unroll 1
  for (int c = 0; c < 8; c++) {
    __syncthreads();  // bar A: sPa(c) ready
    {
      const short8* gb0 =
          (const short8*)memDF + (size_t)((w * 2 + 0) * 64 + c * 8) * 64 + lane;
      const short8* gb1 =
          (const short8*)memDF + (size_t)((w * 2 + 1) * 64 + c * 8) * 64 + lane;
      const bool doG1 = (c < 7);
      const short8* ga = (const short8*)memTbF +
                         (size_t)(((c + 1) * 4 + mslot) * 32) * 64 + lane;
      if (doG1) sacc = (f32x16)0.0f;
#pragma unroll
      for (int k0 = 0; k0 < 8; k0++) {
        int sp = (((k0 << 1) | l5) ^ t15) << 4;
        short8 p0 = *(const short8*)(bp0 + sp);
        short8 p1 = *(const short8*)(bp1 + sp);
        short8 b0 = gb0[k0 * 64];
        short8 b1 = gb1[k0 * 64];
        oacc[0][0] = MFMA32(p0, b0, oacc[0][0]);
        oacc[1][0] = MFMA32(p1, b0, oacc[1][0]);
        oacc[0][1] = MFMA32(p0, b1, oacc[0][1]);
        oacc[1][1] = MFMA32(p1, b1, oacc[1][1]);
        // denominator from the already-loaded P fragments (waves 0/1 only)
        if (w == 0) {
#pragma unroll
          for (int e = 0; e < 8; e++) dsum += bf2f((unsigned short)p0[e]);
        } else if (w == 1) {
#pragma unroll
          for (int e = 0; e < 8; e++) dsum += bf2f((unsigned short)p1[e]);
        }
        if (doG1) {
#pragma unroll
          for (int kq = 0; kq < 4; kq++) {
            int kk = k0 * 4 + kq;
            short8 a = ga[kk * 64];
            int sw = (((kk << 1) | l5) ^ e7) << 4;
            short8 xv = *(const short8*)(bx + sw);
            sacc = MFMA32(a, xv, sacc);
          }
        }
      }
    }
    __syncthreads();  // bar B: sPa(c) consumed by all waves
    if (c < 7) pgen();
  }

  // ---- Denominators -> sPa (dead) ----
  float* sInvF = (float*)sPa;
  if (w == 0) {
    float s = dsum + __shfl_xor(dsum, 32);
    if (lane < 32) sInvF[lane] = 1.0f / s;
  } else if (w == 1) {
    float s = dsum + __shfl_xor(dsum, 32);
    if (lane < 32) sInvF[32 + lane] = 1.0f / s;
  }
  __syncthreads();

  // ---- Epilogue: O * (1/sum) ----
#pragma unroll
  for (int tt = 0; tt < 2; tt++) {
#pragma unroll
    for (int q = 0; q < 16; q++) {
      int token = tt * 32 + (q & 3) + ((q >> 2) << 3) + (l5 << 2);
      float inv = sInvF[token];
      float* op = out + (t0 + token) * (long)D_ + w * 64 + c31;
      op[0] = oacc[tt][0][q] * inv;
      op[32] = oacc[tt][1][q] * inv;
    }
  }
}

extern "C" void kernel_launch(void* const* d_in, const int* in_sizes, int n_in,
                              void* d_out, int out_size, void* d_ws, size_t ws_size,
                              hipStream_t stream) {
  const float* x = (const float*)d_in[0];
  const float* mem = (const float*)d_in[1];
  float* out = (float*)d_out;
  unsigned short* memTbF = (unsigned short*)d_ws;    // 1 MB frag-layout (scaled)
  unsigned short* memDF = memTbF + (size_t)D_ * M_;  // 1 MB frag-layout

  hipLaunchKernelGGL(prep_mem_kernel, dim3((D_ * M_) / 256), dim3(256), 0, stream,
                     mem, memTbF, memDF);
  hipLaunchKernelGGL(fused_kernel, dim3((B_ * N_) / BT), dim3(512), 0, stream,
                     x, memTbF, memDF, out);
}